// Round 6
// baseline (192.115 us; speedup 1.0000x reference)
//
#include <hip/hip_runtime.h>
#include <math.h>
#include <stdint.h>

// VP-SDE Euler-Maruyama forward diffusion (fp32).
// out[0] = x; out[t+1] = a_t * out[t] + b_t * noise[t],  t = 0..99
// beta_t = 0.1 + (t/100)*19.9; a_t = 1 - 0.5*beta_t/100; b_t = sqrt(beta_t)/10.
//
// ~808 MB irreducible traffic -> ~128 us floor @6.3 TB/s copy ceiling.
// R1 199.8 (naive) -> R4 178.5 (reg ping-pong + nt) -> R5 183.1 (launch_bounds
// (256,4) choked the reg pipeline). R6: move the prefetch pipeline into LDS
// via global_load_lds (async DMA, 0 VGPRs): per-wave private double buffer,
// NO barriers, counted vmcnt waits (never 0 in loop). VGPR ~30 -> guaranteed
// 4 blocks/CU, 8 loads/wave always in flight.

#define S_STEPS 100
#define U 4                     // timesteps per window
#define NWIN (S_STEPS / U)      // 25 windows

typedef float f32x4 __attribute__((ext_vector_type(4)));

#define WAITV(n) asm volatile("s_waitcnt vmcnt(" #n ")" ::: "memory")

__device__ __forceinline__ void gl_lds16(const float* g, const float* l) {
    // 16B per lane: LDS dest = wave-uniform base + lane*16 (linear);
    // global src is per-lane. aux=0 (cached reads).
    __builtin_amdgcn_global_load_lds(
        (const __attribute__((address_space(1))) unsigned int*)g,
        (__attribute__((address_space(3))) unsigned int*)l,
        16, 0, 0);
}

__global__ __launch_bounds__(256) void vpsde_fwd_kernel(
    const float* __restrict__ x,
    const float* __restrict__ noise,
    float* __restrict__ out,
    int ne)  // floats per timestep plane (1,048,576)
{
    // [buf][k][wave][lane*4]: 1KB per (buf,k,wave) slot, linear for gl_lds.
    __shared__ __align__(16) float s_noise[2][U][4][256];   // 32 KB
    __shared__ float2 s_ab[S_STEPS];                        // 800 B

    const int tid  = threadIdx.x;
    const int wid  = tid >> 6;
    const int lane = tid & 63;

    if (tid < S_STEPS) {
        const float dt = 0.01f;
        float nt_  = (float)tid * dt;          // (t-1)/S for t=1..S
        float beta = 0.1f + nt_ * 19.9f;
        s_ab[tid] = make_float2(1.0f - 0.5f * beta * dt,   // a_t
                                sqrtf(beta) * 0.1f);       // b_t
    }
    __syncthreads();   // s_ab visible block-wide (only barrier in the kernel)

    const size_t idx4  = (size_t)blockIdx.x * 256 + tid;   // float4 index
    const size_t plane = (size_t)ne;                       // floats per plane

    f32x4 xv = *(const f32x4*)(x + idx4 * 4);
    __builtin_nontemporal_store(xv, (f32x4*)(out + idx4 * 4));  // out[0]=x

    const float* gld = noise + idx4 * 4;   // running per-lane load pointer
    float*       dst = out + plane + idx4 * 4;  // out[t+1] running pointer

    auto issue = [&](int b) {              // 4 async loads -> buffer b
        #pragma unroll
        for (int k = 0; k < U; ++k) {
            gl_lds16(gld, &s_noise[b][k][wid][0]);
            gld += plane;
        }
    };
    auto consume = [&](int b, int t0) {    // 4 fma+store from buffer b
        #pragma unroll
        for (int k = 0; k < U; ++k) {
            float2 ab = s_ab[t0 + k];
            f32x4 nv = *(const f32x4*)&s_noise[b][k][wid][lane * 4];
            xv = ab.x * xv + ab.y * nv;
            __builtin_nontemporal_store(xv, (f32x4*)dst);
            dst += plane;
        }
    };

    // Prologue: 2 windows in flight.
    issue(0);                 // window 0
    issue(1);                 // window 1

    // Window 0: outstanding = [L0(4), L1(4)] -> need L0 done -> vmcnt(4).
    WAITV(4);
    __builtin_amdgcn_sched_barrier(0);
    consume(0, 0);
    __builtin_amdgcn_sched_barrier(0);
    issue(0);                 // window 2

    // Windows 1..23: outstanding = [Lw(4), Sw-1(4), Lw+1(4)] -> vmcnt(8)
    // (vmcnt retires in order: the 4 oldest are this window's loads).
    int b = 1;
    for (int w = 1; w <= NWIN - 2; ++w) {
        WAITV(8);
        __builtin_amdgcn_sched_barrier(0);
        consume(b, w * U);
        __builtin_amdgcn_sched_barrier(0);
        if (w <= NWIN - 3) issue(b);   // refill -> window w+2 (exists)
        b ^= 1;
    }

    // Window 24: outstanding = [L24(4), S23(4)] -> vmcnt(4).
    WAITV(4);
    __builtin_amdgcn_sched_barrier(0);
    consume(b, (NWIN - 1) * U);
}

extern "C" void kernel_launch(void* const* d_in, const int* in_sizes, int n_in,
                              void* d_out, int out_size, void* d_ws, size_t ws_size,
                              hipStream_t stream) {
    const float* x     = (const float*)d_in[0];   // (64,256,64)
    const float* noise = (const float*)d_in[1];   // (100,64,256,64)
    float* out         = (float*)d_out;           // (101,64,256,64)

    const int ne  = in_sizes[0];       // 1,048,576 floats per plane
    const int ne4 = ne / 4;            // 262,144 float4
    const int block = 256;
    const int grid  = ne4 / block;     // 1024 blocks = 4/CU exactly

    vpsde_fwd_kernel<<<grid, block, 0, stream>>>(x, noise, out, ne);
}

// Round 7
// 190.544 us; speedup vs baseline: 1.0082x; 1.0082x over previous
//
#include <hip/hip_runtime.h>
#include <math.h>

// VP-SDE Euler-Maruyama forward diffusion (fp32).
// out[0] = x; out[t+1] = a_t * out[t] + b_t * noise[t],  t = 0..99
// beta_t = 0.1 + (t/100)*19.9; a_t = 1 - 0.5*beta_t/100; b_t = sqrt(beta_t)/10.
//
// Traffic: 404 MB noise read + 404 MB out write (+4 MB x).
// R1 199.8 (naive) -> R4 178.5 (reg ping-pong, nt ld + nt st)
// -> R5 183.1 (cached st + launch_bounds(256,4): confounded, dead end)
// -> R6 192.1 (LDS-DMA pipeline: slower, BUT revealed FETCH=202MB -- cached
//    loads let the 256MB L3 serve ~half the noise across graph replays,
//    because nt stores don't allocate and don't evict it).
// R7: R4 structure, ONE change: loads cached (plain), stores stay nt.
// Expected hbm_bytes ~640MB -> 140-155 us.

#define S_STEPS 100
#define U 5                    // timesteps per window
#define NW (S_STEPS / U)       // 20 windows (even -> clean ping-pong)

typedef float f32x4 __attribute__((ext_vector_type(4)));

__global__ __launch_bounds__(256) void vpsde_fwd_kernel(
    const f32x4* __restrict__ x,
    const f32x4* __restrict__ noise,
    f32x4* __restrict__ out,
    int ne4)  // float4 elements per timestep
{
    __shared__ float s_a[S_STEPS];
    __shared__ float s_b[S_STEPS];

    const int tid = threadIdx.x;
    if (tid < S_STEPS) {
        const float dt = 0.01f;
        float nt_ = (float)tid * dt;          // (t-1)/S for t=1..S
        float beta = 0.1f + nt_ * 19.9f;
        s_a[tid] = 1.0f - 0.5f * beta * dt;
        s_b[tid] = sqrtf(beta) * 0.1f;        // sqrt(beta)*sqrt(dt)
    }
    __syncthreads();

    const int idx = blockIdx.x * blockDim.x + tid;
    if (idx >= ne4) return;

    const f32x4* np_ = noise + idx;
    f32x4* op_ = out + idx;

    f32x4 xv = x[idx];
    __builtin_nontemporal_store(xv, op_);     // out[0] = x

    f32x4 A[U], B[U];

    auto loadw = [&](f32x4* buf, int w0) {
        #pragma unroll
        for (int k = 0; k < U; ++k)
            buf[k] = np_[(size_t)(w0 + k) * ne4];   // CACHED load (L2/L3 fill)
    };
    auto consume = [&](const f32x4* buf, int w0) {
        #pragma unroll
        for (int k = 0; k < U; ++k) {
            const int t = w0 + k;
            const float a = s_a[t];
            const float b = s_b[t];
            xv = a * xv + b * buf[k];          // componentwise fma
            __builtin_nontemporal_store(xv, op_ + (size_t)(t + 1) * ne4);
        }
    };

    // Ping-pong software pipeline: window w+1's loads are issued before
    // window w is consumed, so 5 independent loads stay in flight across
    // every fma+store phase.
    loadw(A, 0);
    for (int w = 0; w < NW; w += 2) {
        loadw(B, (w + 1) * U);                     // prefetch next window
        consume(A, w * U);
        if (w + 2 < NW) loadw(A, (w + 2) * U);     // prefetch window after next
        consume(B, (w + 1) * U);
    }
}

extern "C" void kernel_launch(void* const* d_in, const int* in_sizes, int n_in,
                              void* d_out, int out_size, void* d_ws, size_t ws_size,
                              hipStream_t stream) {
    const float* x     = (const float*)d_in[0];   // (64,256,64)
    const float* noise = (const float*)d_in[1];   // (100,64,256,64)
    float* out         = (float*)d_out;           // (101,64,256,64)

    const int ne  = in_sizes[0];       // 1,048,576 elements per timestep
    const int ne4 = ne / 4;            // 262,144 float4 per timestep

    const int block = 256;
    const int grid  = (ne4 + block - 1) / block;  // 1024 blocks (4/CU)

    vpsde_fwd_kernel<<<grid, block, 0, stream>>>(
        (const f32x4*)x, (const f32x4*)noise, (f32x4*)out, ne4);
}